// Round 1
// baseline (1187.998 us; speedup 1.0000x reference)
//
#include <hip/hip_runtime.h>
#include <stdint.h>

// ---------------------------------------------------------------------------
// Problem constants: B=256, H=W=14, HW=196, TS=0.03, TC=0.07, TP_K=19, TN_K=98
// Padded spatial layout: each image stored as 16x16 cells (1-cell zero halo),
// row index = b*256 + (h+1)*16 + (w+1).  Conv 3x3 SAME == 9 shift-GEMMs with
// uniform row delta (kh-1)*16 + (kw-1); halo cells are physical zeros.
// ---------------------------------------------------------------------------

typedef __attribute__((ext_vector_type(8))) short bf16x8;
typedef __attribute__((ext_vector_type(4))) float f32x4;

__device__ __forceinline__ unsigned short f2bf(float x) {
  unsigned u = __float_as_uint(x);
  unsigned r = u + 0x7FFFu + ((u >> 16) & 1u);   // RNE, no NaN inputs here
  return (unsigned short)(r >> 16);
}
__device__ __forceinline__ float bf2f(unsigned short h) {
  return __uint_as_float(((unsigned)h) << 16);
}

typedef const __attribute__((address_space(1))) void* gptr1_t;
typedef __attribute__((address_space(3))) void* lptr3_t;
__device__ __forceinline__ void gload_lds16(const void* g, void* l) {
  // dest = wave-uniform LDS base + lane*16 (HW rule); src is per-lane.
  __builtin_amdgcn_global_load_lds((gptr1_t)g, (lptr3_t)l, 16, 0, 0);
}

__device__ __forceinline__ float waveSum(float v) {
#pragma unroll
  for (int m = 1; m < 64; m <<= 1) v += __shfl_xor(v, m, 64);
  return v;
}
__device__ __forceinline__ float waveMax(float v) {
#pragma unroll
  for (int m = 1; m < 64; m <<= 1) v = fmaxf(v, __shfl_xor(v, m, 64));
  return v;
}
template <int NW>
__device__ __forceinline__ float blockSum(float v) {
  __shared__ float sh[NW];
  v = waveSum(v);
  int wv = threadIdx.x >> 6, ln = threadIdx.x & 63;
  if (ln == 0) sh[wv] = v;
  __syncthreads();
  float r = 0.f;
#pragma unroll
  for (int w = 0; w < NW; ++w) r += sh[w];
  __syncthreads();
  return r;
}
template <int NW>
__device__ __forceinline__ float blockMax(float v) {
  __shared__ float sh[NW];
  v = waveMax(v);
  int wv = threadIdx.x >> 6, ln = threadIdx.x & 63;
  if (ln == 0) sh[wv] = v;
  __syncthreads();
  float r = -3.4e38f;
#pragma unroll
  for (int w = 0; w < NW; ++w) r = fmaxf(r, sh[w]);
  __syncthreads();
  return r;
}

// ---------------------------------------------------------------------------
// GEMM: C[m,n] = sum_t sum_k A_t[m,k] * B[t,n,k]   (B stored n-major,k-contig)
// 128x128 tile, 4 waves (2x2), 16x16x32 bf16 MFMA, 4x4 frags/wave (m97 shape).
// APAD: A row index goes through the padded-16x16 map (+ per-tap delta).
// OPAD: output row goes through the padded map (conv1 -> padded x1 buffer).
// EPI: 0 = relu->bf16, 1 = bf16, 2 = f32
// ---------------------------------------------------------------------------
template <int K, int NT, int NTOT, int NLD, bool APAD, bool OPAD, int EPI>
__global__ __launch_bounds__(256, 2) void gemm_k(
    const unsigned short* __restrict__ A, const unsigned short* __restrict__ Bw,
    void* __restrict__ C) {
  __shared__ short As[128 * 32];
  __shared__ short Bs[128 * 32];
  const int tid = threadIdx.x;
  const int wave = tid >> 6, lane = tid & 63;
  const int m0 = blockIdx.x * 128, n0 = blockIdx.y * 128;
  const int seg = lane & 3;    // 16B segment within a 64B row
  const int rr = lane >> 2;    // row within 16-row group
  const int wm = wave >> 1, wn = wave & 1;
  const int quad = lane >> 4, tq = lane & 15;

  int asrc[2], bsrc[2];
#pragma unroll
  for (int inst = 0; inst < 2; ++inst) {
    int rloc = wave * 32 + inst * 16 + rr;
    int m = m0 + rloc;
    int sr;
    if (APAD) {
      int b = m / 196, p = m - b * 196, h = p / 14, w = p - h * 14;
      sr = b * 256 + (h + 1) * 16 + (w + 1);
    } else
      sr = m;
    asrc[inst] = sr * K + seg * 8;
    bsrc[inst] = (n0 + rloc) * K + seg * 8;
  }

  f32x4 acc[4][4];
#pragma unroll
  for (int mi = 0; mi < 4; ++mi)
#pragma unroll
    for (int ni = 0; ni < 4; ++ni) {
      f32x4 z = {0.f, 0.f, 0.f, 0.f};
      acc[mi][ni] = z;
    }

  short* As_w0 = &As[(wave * 32) * 32];
  short* As_w1 = &As[(wave * 32 + 16) * 32];
  short* Bs_w0 = &Bs[(wave * 32) * 32];
  short* Bs_w1 = &Bs[(wave * 32 + 16) * 32];

#pragma unroll 1
  for (int t = 0; t < NT; ++t) {
    int adel = 0;
    if (NT > 1) {
      int dh = t / 3 - 1, dw = t - (t / 3) * 3 - 1;
      adel = (dh * 16 + dw) * K;   // uniform shift in padded row space
    }
    const unsigned short* Bt = Bw + (size_t)t * NTOT * K;
#pragma unroll 1
    for (int kc = 0; kc < K / 32; ++kc) {
      int kb = kc * 32;
      __syncthreads();
      gload_lds16(A + asrc[0] + adel + kb, As_w0);
      gload_lds16(A + asrc[1] + adel + kb, As_w1);
      gload_lds16(Bt + bsrc[0] + kb, Bs_w0);
      gload_lds16(Bt + bsrc[1] + kb, Bs_w1);
      __syncthreads();
      bf16x8 af[4], bfr[4];
#pragma unroll
      for (int mi = 0; mi < 4; ++mi)
        af[mi] = *(const bf16x8*)&As[(wm * 64 + mi * 16 + tq) * 32 + quad * 8];
#pragma unroll
      for (int ni = 0; ni < 4; ++ni)
        bfr[ni] = *(const bf16x8*)&Bs[(wn * 64 + ni * 16 + tq) * 32 + quad * 8];
#pragma unroll
      for (int mi = 0; mi < 4; ++mi)
#pragma unroll
        for (int ni = 0; ni < 4; ++ni)
          acc[mi][ni] = __builtin_amdgcn_mfma_f32_16x16x32_bf16(
              af[mi], bfr[ni], acc[mi][ni], 0, 0, 0);
    }
  }

#pragma unroll
  for (int mi = 0; mi < 4; ++mi) {
#pragma unroll
    for (int r = 0; r < 4; ++r) {
      int m = m0 + wm * 64 + mi * 16 + quad * 4 + r;
      int orow;
      if (OPAD) {
        int b = m / 196, p = m - b * 196, h = p / 14, w = p - h * 14;
        orow = b * 256 + (h + 1) * 16 + (w + 1);
      } else
        orow = m;
      size_t obase = (size_t)orow * NLD + n0 + wn * 64 + tq;
#pragma unroll
      for (int ni = 0; ni < 4; ++ni) {
        float v = acc[mi][ni][r];
        size_t idx = obase + ni * 16;
        if (EPI == 0)
          ((unsigned short*)C)[idx] = f2bf(fmaxf(v, 0.f));
        else if (EPI == 1)
          ((unsigned short*)C)[idx] = f2bf(v);
        else
          ((float*)C)[idx] = v;
      }
    }
  }
}

// --------------------------- small kernels ---------------------------------

__global__ void cast_f2b_k(const float* __restrict__ in,
                           unsigned short* __restrict__ out, int n) {
  int i = blockIdx.x * 256 + threadIdx.x;
  if (i < n) out[i] = f2bf(in[i]);
}

// W (512, CIN, 3, 3) fp32 -> out[t][n][k]=W[n][k][t] bf16
template <int CIN>
__global__ void build_wb_k(const float* __restrict__ W,
                           unsigned short* __restrict__ out) {
  int i = blockIdx.x * 256 + threadIdx.x;
  if (i >= 9 * 512 * CIN) return;
  int t = i / (512 * CIN);
  int rem = i - t * (512 * CIN);
  int n = rem / CIN;
  int c = rem - n * CIN;
  out[i] = f2bf(W[(n * CIN + c) * 9 + t]);
}

// ev (256,384,14,14) fp32 -> padded (65536,384) bf16 (halo cells = 0)
__global__ void evpad_k(const float* __restrict__ ev,
                        unsigned short* __restrict__ out) {
  int i = blockIdx.x * 256 + threadIdx.x;  // 65536*384 total
  int pr = i / 384, c = i - pr * 384;
  int b = pr >> 8, cell = pr & 255;
  int h = (cell >> 4) - 1, w = (cell & 15) - 1;
  float v = 0.f;
  if ((unsigned)h < 14u && (unsigned)w < 14u)
    v = ev[(b * 384 + c) * 196 + h * 14 + w];
  out[i] = f2bf(v);
}

// masked mean pool over pixels: indv[b,c] = sum_p fv[b,p,c]*m / sum_p m
__global__ __launch_bounds__(512) void pool_k(
    const unsigned short* __restrict__ fv, const int* __restrict__ masks,
    float* __restrict__ indv) {
  int b = blockIdx.x, tid = threadIdx.x;
  __shared__ float mf[196];
  if (tid < 196) mf[tid] = (float)masks[b * 196 + tid];
  __syncthreads();
  float acc = 0.f, ms = 0.f;
  for (int p = 0; p < 196; ++p) {
    float m = mf[p];
    ms += m;
    if (m != 0.f) acc += bf2f(fv[(size_t)(b * 196 + p) * 512 + tid]);
  }
  indv[b * 512 + tid] = acc / ms;
}

__global__ __launch_bounds__(512) void indnorm_k(
    const float* __restrict__ indv, float* __restrict__ indn,
    unsigned short* __restrict__ indnb) {
  int b = blockIdx.x, tid = threadIdx.x;
  float v = indv[b * 512 + tid];
  float ss = blockSum<8>(v * v);
  float sc = 1.f / fmaxf(sqrtf(ss), 1e-12f);
  float o = v * sc;
  indn[b * 512 + tid] = o;
  indnb[b * 512 + tid] = f2bf(o);
}

// per-pixel channel L2 normalize, in place (bf16)
__global__ __launch_bounds__(256) void pixnorm_k(unsigned short* __restrict__ fv) {
  size_t base = (size_t)blockIdx.x * 512;
  int tid = threadIdx.x;
  float v0 = bf2f(fv[base + tid]), v1 = bf2f(fv[base + 256 + tid]);
  float ss = blockSum<4>(v0 * v0 + v1 * v1);
  float sc = 1.f / fmaxf(sqrtf(ss), 1e-12f);
  fv[base + tid] = f2bf(v0 * sc);
  fv[base + 256 + tid] = f2bf(v1 * sc);
}

// exact k-th largest of the wave's (up to 256) keys via 32-step radix descent
__device__ __forceinline__ float radix_kth(unsigned k0, unsigned k1, unsigned k2,
                                           unsigned k3, int k) {
  unsigned prefix = 0;
  int kk = k;
#pragma unroll 1
  for (int bit = 31; bit >= 0; --bit) {
    unsigned thi = (prefix >> bit) | 1u;
    int c = __popcll(__ballot((k0 >> bit) == thi)) +
            __popcll(__ballot((k1 >> bit) == thi)) +
            __popcll(__ballot((k2 >> bit) == thi)) +
            __popcll(__ballot((k3 >> bit) == thi));
    if (kk <= c)
      prefix |= (1u << bit);
    else
      kk -= c;
  }
  unsigned u = (prefix & 0x80000000u) ? (prefix ^ 0x80000000u) : ~prefix;
  return __uint_as_float(u);
}
__device__ __forceinline__ unsigned sortkey(float x) {
  unsigned u = __float_as_uint(x);
  return u ^ (((int)u >> 31) | 0x80000000u);
}

// per (i, j): thresholds (19th largest / 98th smallest == 99th largest),
// sharp-sigmoid masked means -> SP, SN. Block: i fixed, 64 j's, 4 waves.
__global__ __launch_bounds__(256) void spsn_k(const float* __restrict__ Sij,
                                              float* __restrict__ SP,
                                              float* __restrict__ SN) {
  int i = blockIdx.x, jg = blockIdx.y;
  int tid = threadIdx.x, wave = tid >> 6, lane = tid & 63;
  __shared__ float tile[196 * 65];  // +1 pad: column reads conflict-free
#pragma unroll 1
  for (int it = 0; it < 49; ++it) {
    int lin = it * 256 + tid;
    int p = lin >> 6, j = lin & 63;
    tile[p * 65 + j] = Sij[(size_t)(i * 196 + p) * 256 + jg * 64 + j];
  }
  __syncthreads();
#pragma unroll 1
  for (int jj = 0; jj < 16; ++jj) {
    int j = jj * 4 + wave;
    float v0 = tile[lane * 65 + j];
    float v1 = tile[(lane + 64) * 65 + j];
    float v2 = tile[(lane + 128) * 65 + j];
    bool val3 = lane < 4;
    float v3 = val3 ? tile[(lane + 192) * 65 + j] : 0.f;
    unsigned k0 = sortkey(v0), k1 = sortkey(v1), k2 = sortkey(v2);
    unsigned k3 = val3 ? sortkey(v3) : 0u;   // key 0 unreachable by real data
    float thrP = radix_kth(k0, k1, k2, k3, 19);
    float thrN = radix_kth(k0, k1, k2, k3, 99);
    float spn = 0.f, spd = 0.f, snn = 0.f, snd = 0.f;
    const float invTS = 1.f / 0.03f;
#pragma unroll
    for (int q = 0; q < 4; ++q) {
      float v = (q == 0) ? v0 : (q == 1) ? v1 : (q == 2) ? v2 : v3;
      bool ok = (q < 3) || val3;
      if (ok) {
        float mp = 1.f / (1.f + __expf((thrP - v) * invTS));
        float mn = 1.f / (1.f + __expf((v - thrN) * invTS));
        spn += v * mp;
        spd += mp;
        snn += v * mn;
        snd += mn;
      }
    }
    spn = waveSum(spn); spd = waveSum(spd);
    snn = waveSum(snn); snd = waveSum(snd);
    if (lane == 0) {
      SP[i * 256 + jg * 64 + j] = spn / spd;
      SN[i * 256 + jg * 64 + j] = snn / snd;
    }
  }
}

// blocks 0..255: rows of logits1=[SP|SN]/TC ; 256..511: rows of logits2=[SP^T|SN^T]/TC
__global__ __launch_bounds__(256) void loss12_k(const float* __restrict__ SP,
                                                const float* __restrict__ SN,
                                                float* __restrict__ out) {
  int r = blockIdx.x;
  int i = r & 255;
  bool col = r >= 256;
  int tid = threadIdx.x;
  const float invTC = 1.f / 0.07f;
  float a = (col ? SP[tid * 256 + i] : SP[i * 256 + tid]) * invTC;
  float b = (col ? SN[tid * 256 + i] : SN[i * 256 + tid]) * invTC;
  float mx = blockMax<4>(fmaxf(a, b));
  float se = blockSum<4>(__expf(a - mx) + __expf(b - mx));
  float lse = mx + __logf(se);
  if (tid == 0) {
    float diag = SP[i * 256 + i] * invTC;
    atomicAdd(out, -(diag - lse) * (1.f / 512.f));  // (loss1+loss2)/2
  }
}

// dist*w matrix + row-masked sums (loss3 part)
__global__ __launch_bounds__(256) void dist_k(const float* __restrict__ indv,
                                              const float* __restrict__ indn,
                                              const float* __restrict__ fa,
                                              float* __restrict__ val,
                                              float* __restrict__ out) {
  int i = blockIdx.x, j = threadIdx.x;
  __shared__ float iv[512], inr[512];
  __shared__ float diag_sh;
  iv[j] = indv[i * 512 + j];
  iv[j + 256] = indv[i * 512 + 256 + j];
  inr[j] = indn[i * 512 + j];
  inr[j + 256] = indn[i * 512 + 256 + j];
  __syncthreads();
  float d = 0.f, vv = 0.f;
#pragma unroll 4
  for (int c = 0; c < 512; ++c) {
    float fj = fa[j * 512 + c];
    float df = iv[c] - fj + 1e-6f;
    d += df * df;
    vv += inr[c] * indn[j * 512 + c];
  }
  float w = (i == j) ? 1.f : -vv;
  float x = d * w;
  val[i * 256 + j] = x;
  if (j == i) diag_sh = x;
  float tot = blockSum<4>(x);  // internal barrier publishes diag_sh
  if (j == 0) {
    float rs = diag_sh - (tot - diag_sh) * (1.f / 255.f);
    atomicAdd(out + 1, fmaxf(rs + 0.6f, 0.f) * (1.f / 512.f));
  }
}

__global__ __launch_bounds__(256) void loss4_k(const float* __restrict__ val,
                                               float* __restrict__ out) {
  int j = blockIdx.x, i = threadIdx.x;
  float x = val[i * 256 + j];
  __shared__ float diag_sh;
  if (i == j) diag_sh = x;
  float tot = blockSum<4>(x);
  if (i == 0) {
    float cs = diag_sh - (tot - diag_sh) * (1.f / 255.f);
    atomicAdd(out + 1, fmaxf(cs + 0.6f, 0.f) * (1.f / 512.f));
  }
}

// ---------------------------------------------------------------------------

extern "C" void kernel_launch(void* const* d_in, const int* in_sizes, int n_in,
                              void* d_out, int out_size, void* d_ws,
                              size_t ws_size, hipStream_t stream) {
  (void)in_sizes; (void)n_in; (void)out_size; (void)ws_size;
  const float* ev = (const float*)d_in[0];
  const float* ea = (const float*)d_in[1];
  const int* msk = (const int*)d_in[2];
  const float* Wf1 = (const float*)d_in[3];
  const float* Wf2 = (const float*)d_in[4];
  const float* Wc1 = (const float*)d_in[5];
  const float* Wc2 = (const float*)d_in[6];
  float* out = (float*)d_out;
  char* ws = (char*)d_ws;

  size_t off = 0;
  auto alloc = [&](size_t bytes) {
    void* p = ws + off;
    off = (off + bytes + 255) & ~(size_t)255;
    return p;
  };
  // Region R1: ev padded bf16 (65536x384), later reused as fv bf16 (50176x512)
  unsigned short* evb = (unsigned short*)alloc(51380224);
  unsigned short* fv = evb;
  // Region R2: x1 padded bf16 (65536x512), later reused as Sij f32 (50176x256)
  unsigned short* x1b = (unsigned short*)alloc((size_t)65536 * 512 * 2);
  float* Sij = (float*)x1b;
  unsigned short* wb1 = (unsigned short*)alloc((size_t)9 * 512 * 384 * 2);
  unsigned short* wb2 = (unsigned short*)alloc((size_t)9 * 512 * 512 * 2);
  unsigned short* eab = (unsigned short*)alloc((size_t)256 * 2048 * 2);
  unsigned short* wf1b = (unsigned short*)alloc((size_t)512 * 2048 * 2);
  unsigned short* wf2b = (unsigned short*)alloc((size_t)512 * 512 * 2);
  unsigned short* hb = (unsigned short*)alloc((size_t)256 * 512 * 2);
  float* fa = (float*)alloc((size_t)256 * 512 * 4);
  float* indv = (float*)alloc((size_t)256 * 512 * 4);
  float* indn = (float*)alloc((size_t)256 * 512 * 4);
  unsigned short* indnb = (unsigned short*)alloc((size_t)256 * 512 * 2);
  float* SP = (float*)alloc((size_t)256 * 256 * 4);
  float* SN = (float*)alloc((size_t)256 * 256 * 4);
  float* val = (float*)alloc((size_t)256 * 256 * 4);
  // total ~133.6 MB

  hipMemsetAsync(out, 0, 2 * sizeof(float), stream);
  hipMemsetAsync(x1b, 0, (size_t)65536 * 512 * 2, stream);  // halo rows = 0

  cast_f2b_k<<<2048, 256, 0, stream>>>(ea, eab, 256 * 2048);
  cast_f2b_k<<<4096, 256, 0, stream>>>(Wf1, wf1b, 512 * 2048);
  cast_f2b_k<<<1024, 256, 0, stream>>>(Wf2, wf2b, 512 * 512);
  build_wb_k<384><<<(9 * 512 * 384) / 256, 256, 0, stream>>>(Wc1, wb1);
  build_wb_k<512><<<(9 * 512 * 512) / 256, 256, 0, stream>>>(Wc2, wb2);
  evpad_k<<<(65536 * 384) / 256, 256, 0, stream>>>(ev, evb);

  // conv1: relu, bf16, padded out      (M=50176, N=512, K=9*384)
  gemm_k<384, 9, 512, 512, true, true, 0>
      <<<dim3(392, 4), 256, 0, stream>>>(evb, wb1, x1b);
  // fc1: relu->bf16 ; fc2: f32
  gemm_k<2048, 1, 512, 512, false, false, 0>
      <<<dim3(2, 4), 256, 0, stream>>>(eab, wf1b, hb);
  gemm_k<512, 1, 512, 512, false, false, 2>
      <<<dim3(2, 4), 256, 0, stream>>>(hb, wf2b, fa);
  // conv2: bf16 compact out            (M=50176, N=512, K=9*512)
  gemm_k<512, 9, 512, 512, true, false, 1>
      <<<dim3(392, 4), 256, 0, stream>>>(x1b, wb2, fv);

  pool_k<<<256, 512, 0, stream>>>(fv, msk, indv);
  indnorm_k<<<256, 512, 0, stream>>>(indv, indn, indnb);
  pixnorm_k<<<50176, 256, 0, stream>>>(fv);

  // Sij[(i,p), j] = <fvn[i,p,:], indn[j,:]>   (M=50176, N=256, K=512)
  gemm_k<512, 1, 256, 256, false, false, 2>
      <<<dim3(392, 2), 256, 0, stream>>>(fv, indnb, Sij);

  spsn_k<<<dim3(256, 4), 256, 0, stream>>>(Sij, SP, SN);
  loss12_k<<<512, 256, 0, stream>>>(SP, SN, out);
  dist_k<<<256, 256, 0, stream>>>(indv, indn, fa, val, out);
  loss4_k<<<256, 256, 0, stream>>>(val, out);
}

// Round 2
// 923.888 us; speedup vs baseline: 1.2859x; 1.2859x over previous
//
#include <hip/hip_runtime.h>
#include <stdint.h>

// ---------------------------------------------------------------------------
// Problem constants: B=256, H=W=14, HW=196, TS=0.03, TC=0.07, TP_K=19, TN_K=98
// Padded spatial layout: each image stored as 16x16 cells (1-cell zero halo),
// row index = b*256 + (h+1)*16 + (w+1).  Conv 3x3 SAME == 9 shift-GEMMs with
// uniform row delta (kh-1)*16 + (kw-1); halo cells are physical zeros.
// LDS staging is XOR-swizzled (seg ^= row&7) so MFMA fragment ds_read_b128
// quarter-waves hit all 32 banks (2-way max, free per m136).
// ---------------------------------------------------------------------------

typedef __attribute__((ext_vector_type(8))) short bf16x8;
typedef __attribute__((ext_vector_type(4))) float f32x4;

__device__ __forceinline__ unsigned short f2bf(float x) {
  unsigned u = __float_as_uint(x);
  unsigned r = u + 0x7FFFu + ((u >> 16) & 1u);   // RNE, no NaN inputs here
  return (unsigned short)(r >> 16);
}
__device__ __forceinline__ float bf2f(unsigned short h) {
  return __uint_as_float(((unsigned)h) << 16);
}

typedef const __attribute__((address_space(1))) void* gptr1_t;
typedef __attribute__((address_space(3))) void* lptr3_t;
__device__ __forceinline__ void gload_lds16(const void* g, void* l) {
  // dest = wave-uniform LDS base + lane*16 (HW rule); src is per-lane.
  __builtin_amdgcn_global_load_lds((gptr1_t)g, (lptr3_t)l, 16, 0, 0);
}

__device__ __forceinline__ float waveSum(float v) {
#pragma unroll
  for (int m = 1; m < 64; m <<= 1) v += __shfl_xor(v, m, 64);
  return v;
}
__device__ __forceinline__ float waveMax(float v) {
#pragma unroll
  for (int m = 1; m < 64; m <<= 1) v = fmaxf(v, __shfl_xor(v, m, 64));
  return v;
}
template <int NW>
__device__ __forceinline__ float blockSum(float v) {
  __shared__ float sh[NW];
  v = waveSum(v);
  int wv = threadIdx.x >> 6, ln = threadIdx.x & 63;
  if (ln == 0) sh[wv] = v;
  __syncthreads();
  float r = 0.f;
#pragma unroll
  for (int w = 0; w < NW; ++w) r += sh[w];
  __syncthreads();
  return r;
}
template <int NW>
__device__ __forceinline__ float blockMax(float v) {
  __shared__ float sh[NW];
  v = waveMax(v);
  int wv = threadIdx.x >> 6, ln = threadIdx.x & 63;
  if (ln == 0) sh[wv] = v;
  __syncthreads();
  float r = -3.4e38f;
#pragma unroll
  for (int w = 0; w < NW; ++w) r = fmaxf(r, sh[w]);
  __syncthreads();
  return r;
}

// ---------------------------------------------------------------------------
// GEMM: C[m,n] = sum_t sum_k A_t[m,k] * B[t,n,k]   (B stored n-major,k-contig)
// 128x128 tile, 4 waves (2x2), 16x16x32 bf16 MFMA, 4x4 frags/wave.
// BK=64 (two K-chunks per barrier pair; 8 global_load_lds in flight).
// LDS rows are 128B; 16B segment s of row r stored at slot s^(r&7).
// APAD: A row index goes through the padded-16x16 map (+ per-tap delta).
// OPAD: output row goes through the padded map (conv1 -> padded x1 buffer).
// EPI: 0 = relu->bf16, 1 = bf16, 2 = f32
// ---------------------------------------------------------------------------
template <int K, int NT, int NTOT, int NLD, bool APAD, bool OPAD, int EPI>
__global__ __launch_bounds__(256, 2) void gemm_k(
    const unsigned short* __restrict__ A, const unsigned short* __restrict__ Bw,
    void* __restrict__ C) {
  __shared__ short As[128 * 64];
  __shared__ short Bs[128 * 64];
  const int tid = threadIdx.x;
  const int wave = tid >> 6, lane = tid & 63;
  const int m0 = blockIdx.x * 128, n0 = blockIdx.y * 128;
  const int rr8 = lane >> 3;      // row within 8-row store group
  const int seg = lane & 7;       // 16B segment within a 128B row
  const int gseg = seg ^ rr8;     // XOR swizzle: which global segment we fetch
  const int wm = wave >> 1, wn = wave & 1;
  const int quad = lane >> 4, tq = lane & 15;

  int asrc[4], bsrc[4];
#pragma unroll
  for (int i8 = 0; i8 < 4; ++i8) {
    int rloc = wave * 32 + i8 * 8 + rr8;
    int m = m0 + rloc;
    int sr;
    if (APAD) {
      int b = m / 196, p = m - b * 196, h = p / 14, w = p - h * 14;
      sr = b * 256 + (h + 1) * 16 + (w + 1);
    } else
      sr = m;
    asrc[i8] = sr * K + gseg * 8;
    bsrc[i8] = (n0 + rloc) * K + gseg * 8;
  }

  short* As_st[4];
  short* Bs_st[4];
#pragma unroll
  for (int i8 = 0; i8 < 4; ++i8) {
    As_st[i8] = &As[(wave * 32 + i8 * 8) * 64];
    Bs_st[i8] = &Bs[(wave * 32 + i8 * 8) * 64];
  }

  f32x4 acc[4][4];
#pragma unroll
  for (int mi = 0; mi < 4; ++mi)
#pragma unroll
    for (int ni = 0; ni < 4; ++ni) {
      f32x4 z = {0.f, 0.f, 0.f, 0.f};
      acc[mi][ni] = z;
    }

#pragma unroll 1
  for (int t = 0; t < NT; ++t) {
    int adel = 0;
    if (NT > 1) {
      int dh = t / 3 - 1, dw = t - (t / 3) * 3 - 1;
      adel = (dh * 16 + dw) * K;   // uniform shift in padded row space
    }
    const unsigned short* Bt = Bw + (size_t)t * NTOT * K;
#pragma unroll 1
    for (int kc2 = 0; kc2 < K / 64; ++kc2) {
      int kb = kc2 * 64;
      __syncthreads();
#pragma unroll
      for (int i8 = 0; i8 < 4; ++i8)
        gload_lds16(A + asrc[i8] + adel + kb, As_st[i8]);
#pragma unroll
      for (int i8 = 0; i8 < 4; ++i8)
        gload_lds16(Bt + bsrc[i8] + kb, Bs_st[i8]);
      __syncthreads();
#pragma unroll
      for (int h = 0; h < 2; ++h) {
        bf16x8 af[4], bfr[4];
#pragma unroll
        for (int mi = 0; mi < 4; ++mi) {
          int row = wm * 64 + mi * 16 + tq;
          af[mi] = *(const bf16x8*)&As[row * 64 +
                                       (((h << 2) | quad) ^ (row & 7)) * 8];
        }
#pragma unroll
        for (int ni = 0; ni < 4; ++ni) {
          int row = wn * 64 + ni * 16 + tq;
          bfr[ni] = *(const bf16x8*)&Bs[row * 64 +
                                        (((h << 2) | quad) ^ (row & 7)) * 8];
        }
#pragma unroll
        for (int mi = 0; mi < 4; ++mi)
#pragma unroll
          for (int ni = 0; ni < 4; ++ni)
            acc[mi][ni] = __builtin_amdgcn_mfma_f32_16x16x32_bf16(
                af[mi], bfr[ni], acc[mi][ni], 0, 0, 0);
      }
    }
  }

#pragma unroll
  for (int mi = 0; mi < 4; ++mi) {
#pragma unroll
    for (int r = 0; r < 4; ++r) {
      int m = m0 + wm * 64 + mi * 16 + quad * 4 + r;
      int orow;
      if (OPAD) {
        int b = m / 196, p = m - b * 196, h = p / 14, w = p - h * 14;
        orow = b * 256 + (h + 1) * 16 + (w + 1);
      } else
        orow = m;
      size_t obase = (size_t)orow * NLD + n0 + wn * 64 + tq;
#pragma unroll
      for (int ni = 0; ni < 4; ++ni) {
        float v = acc[mi][ni][r];
        size_t idx = obase + ni * 16;
        if (EPI == 0)
          ((unsigned short*)C)[idx] = f2bf(fmaxf(v, 0.f));
        else if (EPI == 1)
          ((unsigned short*)C)[idx] = f2bf(v);
        else
          ((float*)C)[idx] = v;
      }
    }
  }
}

// --------------------------- prep kernels ----------------------------------

// fused cast of ea (524288) + W_fc1 (1048576) + W_fc2 (262144)
__global__ void prep_cast_k(const float* __restrict__ ea,
                            const float* __restrict__ Wf1,
                            const float* __restrict__ Wf2,
                            unsigned short* __restrict__ eab,
                            unsigned short* __restrict__ wf1b,
                            unsigned short* __restrict__ wf2b) {
  int i = blockIdx.x * 256 + threadIdx.x;
  if (i < 524288)
    eab[i] = f2bf(ea[i]);
  else if (i < 1572864)
    wf1b[i - 524288] = f2bf(Wf1[i - 524288]);
  else
    wf2b[i - 1572864] = f2bf(Wf2[i - 1572864]);
}

// W (512, CIN, 3, 3) fp32 -> out[t][n][k]=W[n][k][t] bf16
template <int CIN>
__global__ void build_wb_k(const float* __restrict__ W,
                           unsigned short* __restrict__ out) {
  int i = blockIdx.x * 256 + threadIdx.x;
  if (i >= 9 * 512 * CIN) return;
  int t = i / (512 * CIN);
  int rem = i - t * (512 * CIN);
  int n = rem / CIN;
  int c = rem - n * CIN;
  out[i] = f2bf(W[(n * CIN + c) * 9 + t]);
}

// ev (256,384,14,14) fp32 -> padded (65536,384) bf16 (halo cells = 0)
__global__ void evpad_k(const float* __restrict__ ev,
                        unsigned short* __restrict__ out) {
  int i = blockIdx.x * 256 + threadIdx.x;  // 65536*384 total
  int pr = i / 384, c = i - pr * 384;
  int b = pr >> 8, cell = pr & 255;
  int h = (cell >> 4) - 1, w = (cell & 15) - 1;
  float v = 0.f;
  if ((unsigned)h < 14u && (unsigned)w < 14u)
    v = ev[(b * 384 + c) * 196 + h * 14 + w];
  out[i] = f2bf(v);
}

// zero only the 60 halo cells per image of x1b (instead of 64MB memset)
__global__ void halo_k(unsigned int* __restrict__ x1u) {
  int r = blockIdx.x;  // 0..15359
  int b = r / 60, c = r - b * 60;
  int cell;
  if (c < 16) cell = c;                       // top row
  else if (c < 32) cell = 240 + (c - 16);     // bottom row
  else if (c < 46) cell = (c - 31) * 16;      // left col, rows 1..14
  else cell = (c - 45) * 16 + 15;             // right col, rows 1..14
  x1u[(size_t)(b * 256 + cell) * 256 + threadIdx.x] = 0u;
}

// --------------------------- pooling / norms -------------------------------

// masked mean pool: 8 waves split pixels, 16B/lane loads, LDS combine
__global__ __launch_bounds__(512) void pool_k(
    const unsigned short* __restrict__ fv, const int* __restrict__ masks,
    float* __restrict__ indv) {
  int b = blockIdx.x;
  int w = threadIdx.x >> 6, lane = threadIdx.x & 63;
  __shared__ float red[8][512];
  __shared__ float msh[8];
  float acc[8] = {0.f, 0.f, 0.f, 0.f, 0.f, 0.f, 0.f, 0.f};
  float msum = 0.f;
  for (int p = w; p < 196; p += 8) {
    float m = (float)masks[b * 196 + p];
    msum += m;
    uint4 d = *(const uint4*)(fv + (size_t)(b * 196 + p) * 512 + lane * 8);
    const unsigned short* hp = (const unsigned short*)&d;
#pragma unroll
    for (int k = 0; k < 8; ++k) acc[k] += m * bf2f(hp[k]);
  }
#pragma unroll
  for (int k = 0; k < 8; ++k) red[w][lane * 8 + k] = acc[k];
  if (lane == 0) msh[w] = msum;
  __syncthreads();
  int tid = threadIdx.x;
  float s = 0.f, mtot = 0.f;
#pragma unroll
  for (int ww = 0; ww < 8; ++ww) {
    s += red[ww][tid];
    mtot += msh[ww];
  }
  indv[b * 512 + tid] = s / mtot;
}

// indn (f32+bf16), plus dist-expansion helpers: ivpb=bf16(iv+eps), Pi=||iv+eps||^2
__global__ __launch_bounds__(512) void indnorm_k(
    const float* __restrict__ indv, float* __restrict__ indn,
    unsigned short* __restrict__ indnb, unsigned short* __restrict__ ivpb,
    float* __restrict__ Pi) {
  int b = blockIdx.x, tid = threadIdx.x;
  float v = indv[b * 512 + tid];
  float ss = blockSum<8>(v * v);
  float sc = 1.f / fmaxf(sqrtf(ss), 1e-12f);
  float o = v * sc;
  indn[b * 512 + tid] = o;
  indnb[b * 512 + tid] = f2bf(o);
  float ve = v + 1e-6f;
  ivpb[b * 512 + tid] = f2bf(ve);
  float p2 = blockSum<8>(ve * ve);
  if (tid == 0) Pi[b] = p2;
}

// fa fp32 -> bf16 copy + Qj=||fa_j||^2
__global__ __launch_bounds__(512) void fanorm_k(const float* __restrict__ fa,
                                                unsigned short* __restrict__ fab,
                                                float* __restrict__ Qj) {
  int b = blockIdx.x, tid = threadIdx.x;
  float v = fa[b * 512 + tid];
  fab[b * 512 + tid] = f2bf(v);
  float q = blockSum<8>(v * v);
  if (tid == 0) Qj[b] = q;
}

// per-pixel inverse channel norm (replaces the full pixnorm pass)
__global__ __launch_bounds__(256) void rownorm_k(
    const unsigned short* __restrict__ fv, float* __restrict__ rn) {
  int row = blockIdx.x * 4 + (threadIdx.x >> 6);
  int lane = threadIdx.x & 63;
  uint4 d = *(const uint4*)(fv + (size_t)row * 512 + lane * 8);
  const unsigned short* hp = (const unsigned short*)&d;
  float ss = 0.f;
#pragma unroll
  for (int k = 0; k < 8; ++k) {
    float x = bf2f(hp[k]);
    ss += x * x;
  }
  ss = waveSum(ss);
  if (lane == 0) rn[row] = 1.f / fmaxf(sqrtf(ss), 1e-12f);
}

// ------------------------------ SP / SN ------------------------------------

// exact (to 2^-24 rel) k-th largest of the wave's 196 keys, 24-bit descent
__device__ __forceinline__ float radix_kth(unsigned k0, unsigned k1, unsigned k2,
                                           unsigned k3, int k) {
  unsigned prefix = 0;
  int kk = k;
#pragma unroll 1
  for (int bit = 31; bit >= 8; --bit) {
    unsigned thi = (prefix >> bit) | 1u;
    int c = __popcll(__ballot((k0 >> bit) == thi)) +
            __popcll(__ballot((k1 >> bit) == thi)) +
            __popcll(__ballot((k2 >> bit) == thi)) +
            __popcll(__ballot((k3 >> bit) == thi));
    if (kk <= c)
      prefix |= (1u << bit);
    else
      kk -= c;
  }
  unsigned u = (prefix & 0x80000000u) ? (prefix ^ 0x80000000u) : ~prefix;
  return __uint_as_float(u);
}
__device__ __forceinline__ unsigned sortkey(float x) {
  unsigned u = __float_as_uint(x);
  return u ^ (((int)u >> 31) | 0x80000000u);
}

// per (i, j): thresholds (19th largest / 98th smallest == 99th largest),
// sharp-sigmoid masked means -> SP, SN. Row scaling by rn fused into staging.
__global__ __launch_bounds__(256) void spsn_k(const float* __restrict__ Sij,
                                              const float* __restrict__ rn,
                                              float* __restrict__ SP,
                                              float* __restrict__ SN) {
  int i = blockIdx.x, jg = blockIdx.y;
  int tid = threadIdx.x, wave = tid >> 6, lane = tid & 63;
  __shared__ float tile[196 * 65];  // +1 pad: column reads conflict-free
#pragma unroll 1
  for (int it = 0; it < 49; ++it) {
    int lin = it * 256 + tid;
    int p = lin >> 6, j = lin & 63;
    tile[p * 65 + j] =
        Sij[(size_t)(i * 196 + p) * 256 + jg * 64 + j] * rn[i * 196 + p];
  }
  __syncthreads();
#pragma unroll 1
  for (int jj = 0; jj < 16; ++jj) {
    int j = jj * 4 + wave;
    float v0 = tile[lane * 65 + j];
    float v1 = tile[(lane + 64) * 65 + j];
    float v2 = tile[(lane + 128) * 65 + j];
    bool val3 = lane < 4;
    float v3 = val3 ? tile[(lane + 192) * 65 + j] : 0.f;
    unsigned k0 = sortkey(v0), k1 = sortkey(v1), k2 = sortkey(v2);
    unsigned k3 = val3 ? sortkey(v3) : 0u;   // key 0 unreachable by real data
    float thrP = radix_kth(k0, k1, k2, k3, 19);
    float thrN = radix_kth(k0, k1, k2, k3, 99);
    float spn = 0.f, spd = 0.f, snn = 0.f, snd = 0.f;
    const float invTS = 1.f / 0.03f;
#pragma unroll
    for (int q = 0; q < 4; ++q) {
      float v = (q == 0) ? v0 : (q == 1) ? v1 : (q == 2) ? v2 : v3;
      bool ok = (q < 3) || val3;
      if (ok) {
        float mp = 1.f / (1.f + __expf((thrP - v) * invTS));
        float mn = 1.f / (1.f + __expf((v - thrN) * invTS));
        spn += v * mp;
        spd += mp;
        snn += v * mn;
        snd += mn;
      }
    }
    spn = waveSum(spn); spd = waveSum(spd);
    snn = waveSum(snn); snd = waveSum(snd);
    if (lane == 0) {
      SP[i * 256 + jg * 64 + j] = spn / spd;
      SN[i * 256 + jg * 64 + j] = snn / snd;
    }
  }
}

// blocks 0..255: rows of logits1=[SP|SN]/TC ; 256..511: rows of logits2
__global__ __launch_bounds__(256) void loss12_k(const float* __restrict__ SP,
                                                const float* __restrict__ SN,
                                                float* __restrict__ out) {
  int r = blockIdx.x;
  int i = r & 255;
  bool col = r >= 256;
  int tid = threadIdx.x;
  const float invTC = 1.f / 0.07f;
  float a = (col ? SP[tid * 256 + i] : SP[i * 256 + tid]) * invTC;
  float b = (col ? SN[tid * 256 + i] : SN[i * 256 + tid]) * invTC;
  float mx = blockMax<4>(fmaxf(a, b));
  float se = blockSum<4>(__expf(a - mx) + __expf(b - mx));
  float lse = mx + __logf(se);
  if (tid == 0) {
    float diag = SP[i * 256 + i] * invTC;
    atomicAdd(out, -(diag - lse) * (1.f / 512.f));  // (loss1+loss2)/2
  }
}

// dist = Pi - 2*X + Qj ; w = (i==j)?1:-V ; row-masked sum -> loss3 part
__global__ __launch_bounds__(256) void distcomb_k(
    const float* __restrict__ Pi, const float* __restrict__ Qj,
    const float* __restrict__ X, const float* __restrict__ V,
    float* __restrict__ val, float* __restrict__ out) {
  int i = blockIdx.x, j = threadIdx.x;
  float d = Pi[i] - 2.f * X[i * 256 + j] + Qj[j];
  float w = (i == j) ? 1.f : -V[i * 256 + j];
  float x = d * w;
  val[i * 256 + j] = x;
  __shared__ float diag_sh;
  if (j == i) diag_sh = x;
  float tot = blockSum<4>(x);  // internal barrier publishes diag_sh
  if (j == 0) {
    float rs = diag_sh - (tot - diag_sh) * (1.f / 255.f);
    atomicAdd(out + 1, fmaxf(rs + 0.6f, 0.f) * (1.f / 512.f));
  }
}

__global__ __launch_bounds__(256) void loss4_k(const float* __restrict__ val,
                                               float* __restrict__ out) {
  int j = blockIdx.x, i = threadIdx.x;
  float x = val[i * 256 + j];
  __shared__ float diag_sh;
  if (i == j) diag_sh = x;
  float tot = blockSum<4>(x);
  if (i == 0) {
    float cs = diag_sh - (tot - diag_sh) * (1.f / 255.f);
    atomicAdd(out + 1, fmaxf(cs + 0.6f, 0.f) * (1.f / 512.f));
  }
}

// ---------------------------------------------------------------------------

extern "C" void kernel_launch(void* const* d_in, const int* in_sizes, int n_in,
                              void* d_out, int out_size, void* d_ws,
                              size_t ws_size, hipStream_t stream) {
  (void)in_sizes; (void)n_in; (void)out_size; (void)ws_size;
  const float* ev = (const float*)d_in[0];
  const float* ea = (const float*)d_in[1];
  const int* msk = (const int*)d_in[2];
  const float* Wf1 = (const float*)d_in[3];
  const float* Wf2 = (const float*)d_in[4];
  const float* Wc1 = (const float*)d_in[5];
  const float* Wc2 = (const float*)d_in[6];
  float* out = (float*)d_out;
  char* ws = (char*)d_ws;

  size_t off = 0;
  auto alloc = [&](size_t bytes) {
    void* p = ws + off;
    off = (off + bytes + 255) & ~(size_t)255;
    return p;
  };
  // Region R1: ev padded bf16 (65536x384), later reused as fv bf16 (50176x512)
  unsigned short* evb = (unsigned short*)alloc(51380224);
  unsigned short* fv = evb;
  // Region R2: x1 padded bf16 (65536x512), later reused as Sij f32 (50176x256)
  unsigned short* x1b = (unsigned short*)alloc((size_t)65536 * 512 * 2);
  float* Sij = (float*)x1b;
  unsigned short* wb1 = (unsigned short*)alloc((size_t)9 * 512 * 384 * 2);
  unsigned short* wb2 = (unsigned short*)alloc((size_t)9 * 512 * 512 * 2);
  unsigned short* eab = (unsigned short*)alloc((size_t)256 * 2048 * 2);
  unsigned short* wf1b = (unsigned short*)alloc((size_t)512 * 2048 * 2);
  unsigned short* wf2b = (unsigned short*)alloc((size_t)512 * 512 * 2);
  unsigned short* hb = (unsigned short*)alloc((size_t)256 * 512 * 2);
  float* fa = (float*)alloc((size_t)256 * 512 * 4);
  float* indv = (float*)alloc((size_t)256 * 512 * 4);
  float* indn = (float*)alloc((size_t)256 * 512 * 4);
  unsigned short* indnb = (unsigned short*)alloc((size_t)256 * 512 * 2);
  unsigned short* ivpb = (unsigned short*)alloc((size_t)256 * 512 * 2);
  unsigned short* fab = (unsigned short*)alloc((size_t)256 * 512 * 2);
  float* Pi = (float*)alloc(256 * 4);
  float* Qj = (float*)alloc(256 * 4);
  float* Xm = (float*)alloc((size_t)256 * 256 * 4);
  float* Vm = (float*)alloc((size_t)256 * 256 * 4);
  float* rn = (float*)alloc((size_t)50176 * 4);
  float* SP = (float*)alloc((size_t)256 * 256 * 4);
  float* SN = (float*)alloc((size_t)256 * 256 * 4);
  float* val = (float*)alloc((size_t)256 * 256 * 4);

  hipMemsetAsync(out, 0, 2 * sizeof(float), stream);

  prep_cast_k<<<7168, 256, 0, stream>>>(ea, Wf1, Wf2, eab, wf1b, wf2b);
  build_wb_k<384><<<(9 * 512 * 384) / 256, 256, 0, stream>>>(Wc1, wb1);
  build_wb_k<512><<<(9 * 512 * 512) / 256, 256, 0, stream>>>(Wc2, wb2);
  evpad_k<<<(65536 * 384) / 256, 256, 0, stream>>>(ev, evb);
  halo_k<<<15360, 256, 0, stream>>>((unsigned int*)x1b);

  // conv1: relu, bf16, padded out      (M=50176, N=512, K=9*384)
  gemm_k<384, 9, 512, 512, true, true, 0>
      <<<dim3(392, 4), 256, 0, stream>>>(evb, wb1, x1b);
  // fc1: relu->bf16 ; fc2: f32
  gemm_k<2048, 1, 512, 512, false, false, 0>
      <<<dim3(2, 4), 256, 0, stream>>>(eab, wf1b, hb);
  gemm_k<512, 1, 512, 512, false, false, 2>
      <<<dim3(2, 4), 256, 0, stream>>>(hb, wf2b, fa);
  // conv2: bf16 compact out            (M=50176, N=512, K=9*512)
  gemm_k<512, 9, 512, 512, true, false, 1>
      <<<dim3(392, 4), 256, 0, stream>>>(x1b, wb2, fv);

  pool_k<<<256, 512, 0, stream>>>(fv, msk, indv);
  fanorm_k<<<256, 512, 0, stream>>>(fa, fab, Qj);
  indnorm_k<<<256, 512, 0, stream>>>(indv, indn, indnb, ivpb, Pi);
  rownorm_k<<<12544, 256, 0, stream>>>(fv, rn);

  // Sij_raw[(i,p), j] = <fv[i,p,:], indn[j,:]>   (M=50176, N=256, K=512)
  gemm_k<512, 1, 256, 256, false, false, 2>
      <<<dim3(392, 2), 256, 0, stream>>>(fv, indnb, Sij);
  // X = (iv+eps) . fa^T ; V = indn . indn^T      (M=N=256, K=512)
  gemm_k<512, 1, 256, 256, false, false, 2>
      <<<dim3(2, 2), 256, 0, stream>>>(ivpb, fab, Xm);
  gemm_k<512, 1, 256, 256, false, false, 2>
      <<<dim3(2, 2), 256, 0, stream>>>(indnb, indnb, Vm);

  spsn_k<<<dim3(256, 4), 256, 0, stream>>>(Sij, rn, SP, SN);
  loss12_k<<<512, 256, 0, stream>>>(SP, SN, out);
  distcomb_k<<<256, 256, 0, stream>>>(Pi, Qj, Xm, Vm, val, out);
  loss4_k<<<256, 256, 0, stream>>>(val, out);
}